// Round 6
// baseline (275.862 us; speedup 1.0000x reference)
//
#include <hip/hip_runtime.h>
#include <math.h>

#define S_LEN 2048
#define D_DIM 128
#define BHN   32
#define NKT   32                  // KV tiles of 64
#define TILE_ELEMS (64 * 128)     // f16 elems per tile (16 KB)
#define LOG2E 1.44269504088896340736f

typedef _Float16 f16;
typedef __attribute__((ext_vector_type(4))) _Float16 f16x4;
typedef __attribute__((ext_vector_type(8))) _Float16 f16x8;
typedef __attribute__((ext_vector_type(4))) float    f32x4;

// ---- prepass: K/V fp32 -> f16 FRAGMENT-MAJOR tiles (frag x 64 lanes x 16B),
// so the attention wave loads MFMA operands as perfectly-coalesced
// global_load_dwordx4 at lane*16 — no LDS staging, no barriers in attn.
__global__ __launch_bounds__(256) void prep_kernel(const float* __restrict__ k,
                                                   const float* __restrict__ v,
                                                   f16* __restrict__ kw,
                                                   f16* __restrict__ vtw) {
  __shared__ f16 Vimg[D_DIM * 64];   // 16 KB transposed+swizzled V image (R2-verified)

  const int bx = blockIdx.x;
  const int bh = bx >> 5;
  const int jt = bx & 31;
  const int t  = threadIdx.x;

  // K frag-major: chunk u = frag*64+lane, frag = ks*4+nt:
  // kw[u*8+i] = K[jt*64 + nt*16 + (lane&15)][ks*32 + (lane>>4)*8 + i]
  {
    const float* kbase = k + ((size_t)bh * S_LEN + jt * 64) * D_DIM;
    f16* ktile = kw + ((size_t)bh * NKT + jt) * (size_t)TILE_ELEMS;
#pragma unroll
    for (int i = 0; i < 4; ++i) {
      int u = i * 256 + t;
      int lane = u & 63, frag = u >> 6;
      int ks = frag >> 2, nt = frag & 3;
      int cc = lane & 15, qq = lane >> 4;
      const float* src = kbase + (nt * 16 + cc) * D_DIM + ks * 32 + qq * 8;
      float4 a = *(const float4*)src;
      float4 b = *(const float4*)(src + 4);
      f16x8 vv;
      vv[0]=(f16)a.x; vv[1]=(f16)a.y; vv[2]=(f16)a.z; vv[3]=(f16)a.w;
      vv[4]=(f16)b.x; vv[5]=(f16)b.y; vv[6]=(f16)b.z; vv[7]=(f16)b.w;
      *(f16x8*)(ktile + (size_t)u * 8) = vv;
    }
  }

  // V: stage transposed swizzled image in LDS, then frag-major copy-out.
  // vtw[u*8+i] = V[jt*64 + ks2*32 + (lane>>4)*8 + i][dt*16 + (lane&15)], frag = ks2*8+dt
  {
    const int rq = t >> 4;
    const int dg = t & 15;
    const float* base = v + (((size_t)bh * S_LEN + jt * 64 + rq * 4) * D_DIM + dg * 8);
    float rows[4][8];
#pragma unroll
    for (int rr = 0; rr < 4; ++rr) {
      float4 aa = *(const float4*)(base + rr * D_DIM);
      float4 bb = *(const float4*)(base + rr * D_DIM + 4);
      rows[rr][0]=aa.x; rows[rr][1]=aa.y; rows[rr][2]=aa.z; rows[rr][3]=aa.w;
      rows[rr][4]=bb.x; rows[rr][5]=bb.y; rows[rr][6]=bb.z; rows[rr][7]=bb.w;
    }
    const int kc = rq >> 1;
    const int kk = (rq & 1) * 4;
#pragma unroll
    for (int dd0 = 0; dd0 < 8; ++dd0) {
      int dd = (dd0 + dg) & 7;
      int d  = dg * 8 + dd;
      f16x4 p;
      p[0]=(f16)rows[0][dd]; p[1]=(f16)rows[1][dd];
      p[2]=(f16)rows[2][dd]; p[3]=(f16)rows[3][dd];
      *(f16x4*)(Vimg + d * 64 + ((kc ^ dd) * 8) + kk) = p;
    }
    __syncthreads();
    f16* vtile = vtw + ((size_t)bh * NKT + jt) * (size_t)TILE_ELEMS;
#pragma unroll
    for (int i = 0; i < 4; ++i) {
      int u = i * 256 + t;
      int lane = u & 63, frag = u >> 6;
      int ks2 = frag >> 3, dt = frag & 7;
      int cc = lane & 15, qq = lane >> 4;
      f16x8 vv = *(const f16x8*)(Vimg + (dt * 16 + cc) * 64 + (((ks2 * 4 + qq) ^ (cc & 7)) * 8));
      *(f16x8*)(vtile + (size_t)u * 8) = vv;
    }
  }
}

// ---- main: flash attention, ZERO barriers. One wave (64 thr) per block,
// block owns a 32-row Q-tile (2 strips of 16). K/V fragments loaded straight
// from the frag-major workspace into registers (coalesced dwordx4, lane*16);
// each frag feeds 2 MFMAs (both strips). P round-trip via 4.3 KB per-wave
// LDS (R5's measured-conflict-free stride-68 XOR layout; within-wave only,
// lgkmcnt-ordered, no barrier). Transposed scores S^T = K Q^T (R4/R5-verified).
__global__ __launch_bounds__(64) void attn_kernel(const float* __restrict__ q,
                                                  const f16* __restrict__ kw,
                                                  const f16* __restrict__ vtw,
                                                  const float* __restrict__ am,
                                                  const float* __restrict__ hm,
                                                  float* __restrict__ out) {
  __shared__ f16 Plds[32 * 68];   // 4352 B, rows stride 68

  const int bx   = blockIdx.x;          // 2048 blocks = 32 bh x 64 qt
  const int bh   = bx & 31;
  const int qt   = 63 - (bx >> 5);      // heavy (long causal span) first
  const int b    = bh >> 4;
  const int h    = bh & 15;
  const int lane = threadIdx.x;
  const int c    = lane & 15;
  const int quad = lane >> 4;
  const int qb   = qt * 32;
  const int jmax = qt >> 1;
  const int e2   = (c & 7) << 1;        // XOR key for P swizzle

  // Q fragments for both strips (pre-scaled by log2e); B operand of S^T = K Q^T
  f16x8 qf[2][4];
#pragma unroll
  for (int s = 0; s < 2; ++s) {
    const float* qsrc = q + (((size_t)bh * S_LEN + qb + s * 16 + c) * D_DIM + quad * 8);
#pragma unroll
    for (int ks = 0; ks < 4; ++ks) {
      float4 a  = *(const float4*)(qsrc + ks * 32);
      float4 bb = *(const float4*)(qsrc + ks * 32 + 4);
      f16x8 vv;
      vv[0]=(f16)(a.x*LOG2E);  vv[1]=(f16)(a.y*LOG2E);  vv[2]=(f16)(a.z*LOG2E);  vv[3]=(f16)(a.w*LOG2E);
      vv[4]=(f16)(bb.x*LOG2E); vv[5]=(f16)(bb.y*LOG2E); vv[6]=(f16)(bb.z*LOG2E); vv[7]=(f16)(bb.w*LOG2E);
      qf[s][ks] = vv;
    }
  }

  const float hmv  = hm[h];
  const float* amp = am + (size_t)b * S_LEN;

  f32x4 zero4; zero4[0]=0.f; zero4[1]=0.f; zero4[2]=0.f; zero4[3]=0.f;
  f32x4 oacc[2][8];
#pragma unroll
  for (int s = 0; s < 2; ++s)
#pragma unroll
    for (int dt = 0; dt < 8; ++dt) oacc[s][dt] = zero4;
  float mrow[2] = {-INFINITY, -INFINITY};
  float lrow[2] = {0.f, 0.f};   // per-quad partial row sums

  const f16* kt0 = kw  + (size_t)bh * NKT * TILE_ELEMS + lane * 8;
  const f16* vt0 = vtw + (size_t)bh * NKT * TILE_ELEMS + lane * 8;

  for (int j = 0; j <= jmax; ++j) {
    const f16* kt = kt0 + (size_t)j * TILE_ELEMS;
    const f16* vt = vt0 + (size_t)j * TILE_ELEMS;

    float amv[4][4];
#pragma unroll
    for (int nt = 0; nt < 4; ++nt) {
      float4 a4 = *(const float4*)(amp + j * 64 + nt * 16 + quad * 4);
      amv[nt][0]=a4.x*LOG2E; amv[nt][1]=a4.y*LOG2E; amv[nt][2]=a4.z*LOG2E; amv[nt][3]=a4.w*LOG2E;
    }

    // S^T = K (Q*log2e)^T; each K frag (coalesced reg load) feeds both strips
    f32x4 sacc[2][4];
#pragma unroll
    for (int s = 0; s < 2; ++s)
#pragma unroll
      for (int nt = 0; nt < 4; ++nt) sacc[s][nt] = zero4;
#pragma unroll
    for (int ks = 0; ks < 4; ++ks) {
#pragma unroll
      for (int nt = 0; nt < 4; ++nt) {
        const f16x8 kf = *(const f16x8*)(kt + (ks * 4 + nt) * 512);
        sacc[0][nt] = __builtin_amdgcn_mfma_f32_16x16x32_f16(kf, qf[0][ks], sacc[0][nt], 0, 0, 0);
        sacc[1][nt] = __builtin_amdgcn_mfma_f32_16x16x32_f16(kf, qf[1][ks], sacc[1][nt], 0, 0, 0);
      }
    }

    // V frag loads issued now — in flight across the whole softmax
    f16x8 vf[16];
#pragma unroll
    for (int f = 0; f < 16; ++f) vf[f] = *(const f16x8*)(vt + f * 512);

    if (j == jmax) {   // causal mask, diagonal tile only (wave-uniform branch)
      const int base0 = (qt & 1) * 32;
#pragma unroll
      for (int s = 0; s < 2; ++s) {
        const int thresh = base0 + s * 16 + c;
#pragma unroll
        for (int nt = 0; nt < 4; ++nt)
#pragma unroll
          for (int r = 0; r < 4; ++r)
            if (nt * 16 + quad * 4 + r > thresh) sacc[s][nt][r] = -INFINITY;
      }
    }

    float alpha[2];
#pragma unroll
    for (int s = 0; s < 2; ++s) {
#pragma unroll
      for (int nt = 0; nt < 4; ++nt)
#pragma unroll
        for (int r = 0; r < 4; ++r) sacc[s][nt][r] += amv[nt][r];

      float m16 = sacc[s][0][0];
#pragma unroll
      for (int nt = 0; nt < 4; ++nt)
#pragma unroll
        for (int r = 0; r < 4; ++r) m16 = fmaxf(m16, sacc[s][nt][r]);
      m16 = fmaxf(m16, __shfl_xor(m16, 16));
      m16 = fmaxf(m16, __shfl_xor(m16, 32));
      float mnew = fmaxf(mrow[s], m16);
      alpha[s] = exp2f(mrow[s] - mnew);
      mrow[s] = mnew;

      float psum = 0.f;
#pragma unroll
      for (int nt = 0; nt < 4; ++nt)
#pragma unroll
        for (int r = 0; r < 4; ++r) {
          sacc[s][nt][r] = exp2f(sacc[s][nt][r] - mnew);
          psum += sacc[s][nt][r];
        }
      lrow[s] = lrow[s] * alpha[s] + psum;

      // P -> per-wave LDS (stride 68 + XOR; measured 0 conflicts in R5)
#pragma unroll
      for (int nt = 0; nt < 4; ++nt) {
        f16x4 p;
        p[0]=(f16)sacc[s][nt][0]; p[1]=(f16)sacc[s][nt][1];
        p[2]=(f16)sacc[s][nt][2]; p[3]=(f16)sacc[s][nt][3];
        int ch = (nt * 4 + quad) ^ e2;
        *(f16x4*)(Plds + (s * 16 + c) * 68 + ch * 4) = p;
      }

      // rescale O accumulator (alpha for row quad*4+r lives at lane c==quad*4+r)
      float al[4];
#pragma unroll
      for (int r = 0; r < 4; ++r) al[r] = __shfl(alpha[s], (lane & 48) | (quad * 4 + r));
#pragma unroll
      for (int dt = 0; dt < 8; ++dt)
#pragma unroll
        for (int r = 0; r < 4; ++r) oacc[s][dt][r] *= al[r];
    }

    // O += P V (A-frags from per-wave Plds; within-wave dep -> lgkmcnt only)
#pragma unroll
    for (int ks2 = 0; ks2 < 2; ++ks2) {
      const int ch2 = (ks2 * 8 + quad * 2) ^ e2;
      const f16x8 af0 = *(const f16x8*)(Plds + c * 68 + ch2 * 4);
      const f16x8 af1 = *(const f16x8*)(Plds + (16 + c) * 68 + ch2 * 4);
#pragma unroll
      for (int dt = 0; dt < 8; ++dt) {
        const f16x8 bf = vf[ks2 * 8 + dt];
        oacc[0][dt] = __builtin_amdgcn_mfma_f32_16x16x32_f16(af0, bf, oacc[0][dt], 0, 0, 0);
        oacc[1][dt] = __builtin_amdgcn_mfma_f32_16x16x32_f16(af1, bf, oacc[1][dt], 0, 0, 0);
      }
    }
  }

  // epilogue: reduce l across quads, out = head_mask * O / l
#pragma unroll
  for (int s = 0; s < 2; ++s) {
    float l = lrow[s];
    l += __shfl_xor(l, 16);
    l += __shfl_xor(l, 32);
    float linv = hmv / l;
    float rinv[4];
#pragma unroll
    for (int r = 0; r < 4; ++r) rinv[r] = __shfl(linv, (lane & 48) | (quad * 4 + r));
    float* obase = out + (((size_t)bh * S_LEN + qb + s * 16) * D_DIM);
#pragma unroll
    for (int dt = 0; dt < 8; ++dt)
#pragma unroll
      for (int r = 0; r < 4; ++r)
        obase[(quad * 4 + r) * D_DIM + dt * 16 + c] = oacc[s][dt][r] * rinv[r];
  }
}

extern "C" void kernel_launch(void* const* d_in, const int* in_sizes, int n_in,
                              void* d_out, int out_size, void* d_ws, size_t ws_size,
                              hipStream_t stream) {
  const float* q  = (const float*)d_in[0];
  const float* k  = (const float*)d_in[1];
  const float* v  = (const float*)d_in[2];
  const float* am = (const float*)d_in[3];
  const float* hm = (const float*)d_in[4];
  float* out = (float*)d_out;

  f16* kw  = (f16*)d_ws;                              // 16.78 MB
  f16* vtw = kw + (size_t)BHN * S_LEN * D_DIM;        // 16.78 MB

  prep_kernel<<<1024, 256, 0, stream>>>(k, v, kw, vtw);
  attn_kernel<<<2048, 64, 0, stream>>>(q, kw, vtw, am, hm, out);
}

// Round 7
// 231.179 us; speedup vs baseline: 1.1933x; 1.1933x over previous
//
#include <hip/hip_runtime.h>
#include <math.h>

#define S_LEN 2048
#define D_DIM 128
#define BHN   32
#define NKT   32                  // KV tiles of 64
#define TILE_ELEMS (64 * 128)     // f16 elems per tile (16 KB)
#define LOG2E 1.44269504088896340736f

typedef _Float16 f16;
typedef __attribute__((ext_vector_type(4))) _Float16 f16x4;
typedef __attribute__((ext_vector_type(8))) _Float16 f16x8;
typedef __attribute__((ext_vector_type(4))) float    f32x4;

// ---- prepass: K/V fp32 -> f16 FRAGMENT-MAJOR tiles (frag x 64 lanes x 16B);
// attention waves load MFMA operands as coalesced global_load_dwordx4.
// (unchanged from R6 — correctness-proven)
__global__ __launch_bounds__(256) void prep_kernel(const float* __restrict__ k,
                                                   const float* __restrict__ v,
                                                   f16* __restrict__ kw,
                                                   f16* __restrict__ vtw) {
  __shared__ f16 Vimg[D_DIM * 64];

  const int bx = blockIdx.x;
  const int bh = bx >> 5;
  const int jt = bx & 31;
  const int t  = threadIdx.x;

  // K frag-major: u = (ks*4+nt)*64+lane: kw[u*8+i] = K[nt*16+(lane&15)][ks*32+(lane>>4)*8+i]
  {
    const float* kbase = k + ((size_t)bh * S_LEN + jt * 64) * D_DIM;
    f16* ktile = kw + ((size_t)bh * NKT + jt) * (size_t)TILE_ELEMS;
#pragma unroll
    for (int i = 0; i < 4; ++i) {
      int u = i * 256 + t;
      int lane = u & 63, frag = u >> 6;
      int ks = frag >> 2, nt = frag & 3;
      int cc = lane & 15, qq = lane >> 4;
      const float* src = kbase + (nt * 16 + cc) * D_DIM + ks * 32 + qq * 8;
      float4 a = *(const float4*)src;
      float4 b = *(const float4*)(src + 4);
      f16x8 vv;
      vv[0]=(f16)a.x; vv[1]=(f16)a.y; vv[2]=(f16)a.z; vv[3]=(f16)a.w;
      vv[4]=(f16)b.x; vv[5]=(f16)b.y; vv[6]=(f16)b.z; vv[7]=(f16)b.w;
      *(f16x8*)(ktile + (size_t)u * 8) = vv;
    }
  }

  // V frag-major: u = (ks2*8+dt)*64+lane:
  // vtw[u*8+i] = V[ks2*32+(lane>>4)*8+i][dt*16+(lane&15)]
  {
    const int rq = t >> 4;
    const int dg = t & 15;
    const float* base = v + (((size_t)bh * S_LEN + jt * 64 + rq * 4) * D_DIM + dg * 8);
    float rows[4][8];
#pragma unroll
    for (int rr = 0; rr < 4; ++rr) {
      float4 aa = *(const float4*)(base + rr * D_DIM);
      float4 bb = *(const float4*)(base + rr * D_DIM + 4);
      rows[rr][0]=aa.x; rows[rr][1]=aa.y; rows[rr][2]=aa.z; rows[rr][3]=aa.w;
      rows[rr][4]=bb.x; rows[rr][5]=bb.y; rows[rr][6]=bb.z; rows[rr][7]=bb.w;
    }
    const int kc = rq >> 1;
    const int kk = (rq & 1) * 4;
#pragma unroll
    for (int dd0 = 0; dd0 < 8; ++dd0) {
      int dd = (dd0 + dg) & 7;
      int d  = dg * 8 + dd;
      f16x4 p;
      p[0]=(f16)rows[0][dd]; p[1]=(f16)rows[1][dd];
      p[2]=(f16)rows[2][dd]; p[3]=(f16)rows[3][dd];
      *(f16x4*)(Vimg + d * 64 + ((kc ^ dd) * 8) + kk) = p;
    }
    __syncthreads();
    f16* vtile = vtw + ((size_t)bh * NKT + jt) * (size_t)TILE_ELEMS;
#pragma unroll
    for (int i = 0; i < 4; ++i) {
      int u = i * 256 + t;
      int lane = u & 63, frag = u >> 6;
      int ks2 = frag >> 3, dt = frag & 7;
      int cc = lane & 15, qq = lane >> 4;
      f16x8 vv = *(const f16x8*)(Vimg + (dt * 16 + cc) * 64 + (((ks2 * 4 + qq) ^ (cc & 7)) * 8));
      *(f16x8*)(vtile + (size_t)u * 8) = vv;
    }
  }
}

// ---- main: flash attention, ZERO barriers, direct-register K/V, 4-wave blocks.
// 1024 blocks x 4 waves = 4096 waves (R4's winning parallelism); each block's
// 4 waves read IDENTICAL K/V addresses -> L1 serves ~3/4. LDS holds only the
// per-wave P round-trip (4 KB/wave-iter vs R4's 44 KB -> LDS pipe unloaded).
// Transposed scores S^T = K Q^T (R4-R6 proven numerics).
__global__ __launch_bounds__(256) void attn_kernel(const float* __restrict__ q,
                                                   const f16* __restrict__ kw,
                                                   const f16* __restrict__ vtw,
                                                   const float* __restrict__ am,
                                                   const float* __restrict__ hm,
                                                   float* __restrict__ out) {
  __shared__ f16 Plds[64 * 68];   // 8704 B, per-wave 16-row slices, stride 68

  const int bx   = blockIdx.x;          // 1024 blocks = 32 qi x 32 bh
  const int bh   = bx & 31;
  // reflected qi mapping: any {m, m+8, m+16, m+24} coset of u sums to 62
  // -> per-CU iteration load is constant under round-robin dispatch.
  const int u    = bx >> 5;
  const int ui   = u & 7, uj = u >> 3;
  const int qi   = (uj & 1) ? (uj * 8 + 7 - ui) : (uj * 8 + ui);
  const int b    = bh >> 4;
  const int h    = bh & 15;
  const int t    = threadIdx.x;
  const int w    = t >> 6;
  const int lane = t & 63;
  const int c    = lane & 15;
  const int quad = lane >> 4;
  const int qb   = qi * 64;
  const int R    = w * 16 + c;          // this lane's Q-row in the 64-row tile
  const int e2   = (c & 7) << 1;        // P swizzle key (R5: measured 0 conflicts)

  // broadcast-shuffle indices for alpha/l (lane holding q-row quad*4+r data)
  int sidx[4];
#pragma unroll
  for (int r = 0; r < 4; ++r) sidx[r] = (lane & 48) | (quad * 4 + r);

  // Q fragments (pre-scaled by log2e); B operand of S^T = K Q^T
  f16x8 qf[4];
  {
    const float* qsrc = q + (((size_t)bh * S_LEN + qb + R) * D_DIM + quad * 8);
#pragma unroll
    for (int ks = 0; ks < 4; ++ks) {
      float4 a  = *(const float4*)(qsrc + ks * 32);
      float4 bb = *(const float4*)(qsrc + ks * 32 + 4);
      f16x8 vv;
      vv[0]=(f16)(a.x*LOG2E);  vv[1]=(f16)(a.y*LOG2E);  vv[2]=(f16)(a.z*LOG2E);  vv[3]=(f16)(a.w*LOG2E);
      vv[4]=(f16)(bb.x*LOG2E); vv[5]=(f16)(bb.y*LOG2E); vv[6]=(f16)(bb.z*LOG2E); vv[7]=(f16)(bb.w*LOG2E);
      qf[ks] = vv;
    }
  }

  const float hmv  = hm[h];
  const float* amp = am + (size_t)b * S_LEN;

  f32x4 zero4; zero4[0]=0.f; zero4[1]=0.f; zero4[2]=0.f; zero4[3]=0.f;
  f32x4 oacc[8];
#pragma unroll
  for (int dt = 0; dt < 8; ++dt) oacc[dt] = zero4;
  float mrow = -INFINITY;
  float lrow = 0.f;                     // per-quad partial row sum

  const f16* kt0 = kw  + (size_t)bh * NKT * TILE_ELEMS + lane * 8;
  const f16* vt0 = vtw + (size_t)bh * NKT * TILE_ELEMS + lane * 8;

  for (int j = 0; j <= qi; ++j) {
    const f16* kt = kt0 + (size_t)j * TILE_ELEMS;
    const f16* vt = vt0 + (size_t)j * TILE_ELEMS;

    float amv[4][4];
#pragma unroll
    for (int nt = 0; nt < 4; ++nt) {
      float4 a4 = *(const float4*)(amp + j * 64 + nt * 16 + quad * 4);
      amv[nt][0]=a4.x*LOG2E; amv[nt][1]=a4.y*LOG2E; amv[nt][2]=a4.z*LOG2E; amv[nt][3]=a4.w*LOG2E;
    }

    // S^T = K (Q*log2e)^T; K frags straight from global (coalesced dwordx4)
    f32x4 sacc[4];
#pragma unroll
    for (int nt = 0; nt < 4; ++nt) sacc[nt] = zero4;
#pragma unroll
    for (int ks = 0; ks < 4; ++ks) {
#pragma unroll
      for (int nt = 0; nt < 4; ++nt) {
        const f16x8 kf = *(const f16x8*)(kt + (ks * 4 + nt) * 512);
        sacc[nt] = __builtin_amdgcn_mfma_f32_16x16x32_f16(kf, qf[ks], sacc[nt], 0, 0, 0);
      }
    }

    // V frag loads issued now — in flight across the softmax
    f16x8 vf[16];
#pragma unroll
    for (int f = 0; f < 16; ++f) vf[f] = *(const f16x8*)(vt + f * 512);

    if (j == qi) {   // causal mask, diagonal tile only (wave-uniform branch)
#pragma unroll
      for (int nt = 0; nt < 4; ++nt)
#pragma unroll
        for (int r = 0; r < 4; ++r)
          if (nt * 16 + quad * 4 + r > R) sacc[nt][r] = -INFINITY;
    }
#pragma unroll
    for (int nt = 0; nt < 4; ++nt)
#pragma unroll
      for (int r = 0; r < 4; ++r) sacc[nt][r] += amv[nt][r];

    // online softmax: in-lane max over 16 kv, 2 shuffles across quads
    float m16 = sacc[0][0];
#pragma unroll
    for (int nt = 0; nt < 4; ++nt)
#pragma unroll
      for (int r = 0; r < 4; ++r) m16 = fmaxf(m16, sacc[nt][r]);
    m16 = fmaxf(m16, __shfl_xor(m16, 16));
    m16 = fmaxf(m16, __shfl_xor(m16, 32));
    float mnew  = fmaxf(mrow, m16);
    float alpha = exp2f(mrow - mnew);
    mrow = mnew;

    float psum = 0.f;
#pragma unroll
    for (int nt = 0; nt < 4; ++nt)
#pragma unroll
      for (int r = 0; r < 4; ++r) {
        sacc[nt][r] = exp2f(sacc[nt][r] - mnew);
        psum += sacc[nt][r];
      }
    lrow = lrow * alpha + psum;

    // P -> per-wave LDS slice (stride 68 + even-XOR; R5-measured 0 conflicts)
#pragma unroll
    for (int nt = 0; nt < 4; ++nt) {
      f16x4 p;
      p[0]=(f16)sacc[nt][0]; p[1]=(f16)sacc[nt][1];
      p[2]=(f16)sacc[nt][2]; p[3]=(f16)sacc[nt][3];
      int ch = (nt * 4 + quad) ^ e2;
      *(f16x4*)(Plds + R * 68 + ch * 4) = p;
    }

    // rescale O accumulator
    float al[4];
#pragma unroll
    for (int r = 0; r < 4; ++r) al[r] = __shfl(alpha, sidx[r]);
#pragma unroll
    for (int dt = 0; dt < 8; ++dt)
#pragma unroll
      for (int r = 0; r < 4; ++r) oacc[dt][r] *= al[r];

    // O += P V (A-frags from per-wave Plds; within-wave dep -> lgkmcnt only)
#pragma unroll
    for (int ks2 = 0; ks2 < 2; ++ks2) {
      const int ch2 = (ks2 * 8 + quad * 2) ^ e2;
      const f16x8 af = *(const f16x8*)(Plds + R * 68 + ch2 * 4);
#pragma unroll
      for (int dt = 0; dt < 8; ++dt)
        oacc[dt] = __builtin_amdgcn_mfma_f32_16x16x32_f16(af, vf[ks2 * 8 + dt], oacc[dt], 0, 0, 0);
    }
  }

  // epilogue: reduce l across quads, out = head_mask * O / l
  lrow += __shfl_xor(lrow, 16);
  lrow += __shfl_xor(lrow, 32);
  float linv = hmv / lrow;
  float rinv[4];
#pragma unroll
  for (int r = 0; r < 4; ++r) rinv[r] = __shfl(linv, sidx[r]);

  float* obase = out + (((size_t)bh * S_LEN + qb + w * 16) * D_DIM);
#pragma unroll
  for (int dt = 0; dt < 8; ++dt)
#pragma unroll
    for (int r = 0; r < 4; ++r)
      obase[(quad * 4 + r) * D_DIM + dt * 16 + c] = oacc[dt][r] * rinv[r];
}

extern "C" void kernel_launch(void* const* d_in, const int* in_sizes, int n_in,
                              void* d_out, int out_size, void* d_ws, size_t ws_size,
                              hipStream_t stream) {
  const float* q  = (const float*)d_in[0];
  const float* k  = (const float*)d_in[1];
  const float* v  = (const float*)d_in[2];
  const float* am = (const float*)d_in[3];
  const float* hm = (const float*)d_in[4];
  float* out = (float*)d_out;

  f16* kw  = (f16*)d_ws;                              // 16.78 MB
  f16* vtw = kw + (size_t)BHN * S_LEN * D_DIM;        // 16.78 MB

  prep_kernel<<<1024, 256, 0, stream>>>(k, v, kw, vtw);
  attn_kernel<<<1024, 256, 0, stream>>>(q, kw, vtw, am, hm, out);
}